// Round 5
// baseline (256.614 us; speedup 1.0000x reference)
//
#include <hip/hip_runtime.h>
#include <math.h>

#define BB 32
#define MM 10
#define NNODES 1010
#define DD 128
#define RPB 16                          // node rows per tile in k_back
#define NG 64                           // ceil(1010/16)

// ---------------------------------------------------------------------------
// k_front (49 blocks x 512 threads), one launch, three independent roles:
//   blocks 0..31  : full agent pipeline for batch b = blockIdx.x
//                   thread t -> (d = t>>2, q = t&3); weight ROW slices in
//                   registers (contiguous reads, no transpose); K-partials
//                   reduced with __shfl_xor over the 4-lane q group.
//   blocks 32..47 : wnT[k][d] = W_final[d][k]   (transpose for k_back)
//   block  48     : v_pref[d] = dot(W_final[d,128:256], W_pref)
// ---------------------------------------------------------------------------
__global__ __launch_bounds__(512) void k_front(
    const float* __restrict__ locs,      // (B, 1010, 2)
    const float* __restrict__ capacity,  // (B, 10)
    const float* __restrict__ speed,     // (B, 10)
    const float* __restrict__ W_depot,   // (128, 2)
    const float* __restrict__ W_posproj, // (128, 128)
    const float* __restrict__ alpha,     // (1,)
    const float* __restrict__ W_agents,  // (128, 4)
    const float* __restrict__ W_da,      // (128, 256)
    const float* __restrict__ W_pref,    // (128, 1)
    const float* __restrict__ W_final,   // (128, 384)
    float* __restrict__ out_nodes,       // (B, 1010, 128)
    float* __restrict__ ws_daWd,         // (B, 10, 128)
    float* __restrict__ ws_wnT,          // (128, 128)
    float* __restrict__ ws_vpref)        // (128,)
{
    const int bk = blockIdx.x;
    const int t = threadIdx.x;

    if (bk < BB) {
        const int b = bk;
        const int d = t >> 2;        // 0..127
        const int q = t & 3;         // K-quarter

        __shared__ float pe_s[MM][DD];     // 5 KB
        __shared__ float cat_s[2 * DD];    // [dep | ag]
        __shared__ float da_s[DD];

        // positional encodings for all (m, k)
        for (int idx = t; idx < MM * DD; idx += 512) {
            const int m = idx >> 7;
            const int k = idx & (DD - 1);
            const int i = k >> 1;
            const float div = expf((float)(2 * i) * (-logf(10000.0f) / (float)DD));
            const float ang = (float)m * div;
            pe_s[m][k] = (k & 1) ? cosf(ang) : sinf(ang);
        }

        // weight ROW slices for this (d, q) -> registers (contiguous loads)
        float4 wpp[8], wfd[8], wda[16];
        {
            const float4* p = (const float4*)(W_posproj + (size_t)d * DD + q * 32);
            #pragma unroll
            for (int i = 0; i < 8; ++i) wpp[i] = p[i];
        }
        {
            const float4* p = (const float4*)(W_da + (size_t)d * 256 + q * 64);
            #pragma unroll
            for (int i = 0; i < 16; ++i) wda[i] = p[i];
        }
        {
            const float4* p = (const float4*)(W_final + (size_t)d * 384 + 256 + q * 32);
            #pragma unroll
            for (int i = 0; i < 8; ++i) wfd[i] = p[i];
        }
        const float wd0 = W_depot[d * 2 + 0], wd1 = W_depot[d * 2 + 1];
        const float wa0 = W_agents[d * 4 + 0], wa1 = W_agents[d * 4 + 1];
        const float wa2 = W_agents[d * 4 + 2], wa3 = W_agents[d * 4 + 3];
        const float al = alpha[0];
        __syncthreads();

        for (int m = 0; m < MM; ++m) {
            // peproj partial over this q-slice
            float pp = 0.0f;
            {
                const float4* pe4 = (const float4*)(&pe_s[m][q * 32]);
                #pragma unroll
                for (int i = 0; i < 8; ++i) {
                    const float4 w = wpp[i], x = pe4[i];
                    pp = fmaf(w.x, x.x, fmaf(w.y, x.y, fmaf(w.z, x.z, fmaf(w.w, x.w, pp))));
                }
            }
            pp += __shfl_xor(pp, 1, 4);
            pp += __shfl_xor(pp, 2, 4);

            if (q == 0) {
                const float lx = locs[((size_t)b * NNODES + m) * 2 + 0];
                const float ly = locs[((size_t)b * NNODES + m) * 2 + 1];
                const float dep = fmaf(lx, wd0, fmaf(ly, wd1, al * pp));
                const float cap = capacity[b * MM + m] * (1.0f / 40.0f);
                const float spd = speed[b * MM + m];
                const float ag = fmaf(lx, wa0, fmaf(ly, wa1,
                                 fmaf(cap, wa2, spd * wa3)));
                out_nodes[((size_t)b * NNODES + m) * DD + d] = ag;
                cat_s[d] = dep;
                cat_s[DD + d] = ag;
            }
            __syncthreads();

            // da partial: k in [q*64, q*64+64)
            float da = 0.0f;
            {
                const float4* c4 = (const float4*)(cat_s + q * 64);
                #pragma unroll
                for (int i = 0; i < 16; ++i) {
                    const float4 w = wda[i], x = c4[i];
                    da = fmaf(w.x, x.x, fmaf(w.y, x.y, fmaf(w.z, x.z, fmaf(w.w, x.w, da))));
                }
            }
            da += __shfl_xor(da, 1, 4);
            da += __shfl_xor(da, 2, 4);
            if (q == 0) da_s[d] = da;
            __syncthreads();

            // daWd partial: k in [q*32, q*32+32)
            float dw = 0.0f;
            {
                const float4* c4 = (const float4*)(da_s + q * 32);
                #pragma unroll
                for (int i = 0; i < 8; ++i) {
                    const float4 w = wfd[i], x = c4[i];
                    dw = fmaf(w.x, x.x, fmaf(w.y, x.y, fmaf(w.z, x.z, fmaf(w.w, x.w, dw))));
                }
            }
            dw += __shfl_xor(dw, 1, 4);
            dw += __shfl_xor(dw, 2, 4);
            if (q == 0)
                ws_daWd[(b * MM + m) * DD + d] = dw;
            __syncthreads();   // protect cat_s/da_s for next m
        }
    } else if (bk < 48) {
        // transpose Wn: 8 k-rows per block
        const int d = t & (DD - 1);
        const int j = t >> 7;            // 0..3
        const int k0 = (bk - 32) * 8;
        #pragma unroll
        for (int l = 0; l < 2; ++l) {
            const int k = k0 + j * 2 + l;
            ws_wnT[k * DD + d] = W_final[(size_t)d * 384 + k];
        }
    } else {
        if (t < DD) {
            const int d = t;
            float vp = 0.0f;
            const float4* w = (const float4*)(W_final + (size_t)d * 384 + DD);
            const float4* p = (const float4*)W_pref;
            #pragma unroll
            for (int k4 = 0; k4 < 32; ++k4) {
                const float4 a = w[k4], bb = p[k4];
                vp = fmaf(a.x, bb.x, fmaf(a.y, bb.y, fmaf(a.z, bb.z, fmaf(a.w, bb.w, vp))));
            }
            ws_vpref[d] = vp;
        }
    }
}

// ---------------------------------------------------------------------------
// k_back: fused node-embedding + gemv + expansion. 16-row tiles, 2048 blocks
// (8/CU) for fine-grained store/compute overlap. Regular (cached) stores.
// ---------------------------------------------------------------------------
__global__ __launch_bounds__(256) void k_back(
    const float* __restrict__ locs,      // (B, 1010, 2)
    const float* __restrict__ demand,    // (B, 1, 1010)
    const float* __restrict__ pref,      // (B, 10, 1010)
    const float* __restrict__ W_clients, // (128, 5)
    const float* __restrict__ wnT,       // (128, 128)
    const float* __restrict__ ws_daWd,   // (B, 10, 128)
    const float* __restrict__ ws_vpref,  // (128,)
    float* __restrict__ out_nodes,       // (B, 1010, 128)
    float* __restrict__ out_comb)        // (B, 10, 1010, 128)
{
    const int g = blockIdx.x;
    const int b = blockIdx.y;
    const int t = threadIdx.x;
    const int n0 = g * RPB;

    __shared__ float rows[RPB][DD];      // 8 KB
    __shared__ float feat[RPB][5];
    __shared__ float pref_s[MM][RPB];    // 640 B

    if (t < RPB) {
        const int node = n0 + t;
        if (node < NNODES && node >= MM) {
            const float cx = locs[((size_t)b * NNODES + node) * 2 + 0];
            const float cy = locs[((size_t)b * NNODES + node) * 2 + 1];
            const float d0x = locs[((size_t)b * NNODES + 0) * 2 + 0];
            const float d0y = locs[((size_t)b * NNODES + 0) * 2 + 1];
            const float dx = cx - d0x;
            const float dy = cy - d0y;
            feat[t][0] = cx;
            feat[t][1] = cy;
            feat[t][2] = demand[(size_t)b * NNODES + node] * (1.0f / 40.0f);
            feat[t][3] = sqrtf(fmaf(dx, dx, dy * dy));
            feat[t][4] = atan2f(dy, dx);
        }
    }
    if (t < MM * RPB) {
        const int mm = t >> 4;
        const int rr = t & 15;
        const int node = n0 + rr;
        pref_s[mm][rr] = (node < NNODES)
            ? pref[(size_t)(b * MM + mm) * NNODES + node] : 0.0f;
    }
    __syncthreads();

    // phase A: rows[r][d] = nodes_embedding
    {
        const int d = t & (DD - 1);
        const int h = t >> 7;
        const float wc0 = W_clients[d * 5 + 0];
        const float wc1 = W_clients[d * 5 + 1];
        const float wc2 = W_clients[d * 5 + 2];
        const float wc3 = W_clients[d * 5 + 3];
        const float wc4 = W_clients[d * 5 + 4];
        #pragma unroll
        for (int i = 0; i < RPB / 2; ++i) {
            const int r = h * (RPB / 2) + i;
            const int node = n0 + r;
            float val = 0.0f;
            if (node < NNODES) {
                if (node < MM) {
                    val = out_nodes[((size_t)b * NNODES + node) * DD + d];
                } else {
                    val = fmaf(feat[r][0], wc0,
                          fmaf(feat[r][1], wc1,
                          fmaf(feat[r][2], wc2,
                          fmaf(feat[r][3], wc3,
                               feat[r][4] * wc4))));
                    out_nodes[((size_t)b * NNODES + node) * DD + d] = val;
                }
            }
            rows[r][d] = val;
        }
    }

    // hoist epilogue operands so phase-C stores can issue immediately
    const int c = t & 31;
    const int s = t >> 5;            // 0..7 -> rows s*2, s*2+1
    const int col = c * 4;
    const float4 vp = *(const float4*)(ws_vpref + col);
    float4 dawd[MM];
    #pragma unroll
    for (int mm = 0; mm < MM; ++mm)
        dawd[mm] = *(const float4*)(ws_daWd + (size_t)(b * MM + mm) * DD + col);

    __syncthreads();

    // phase B: acc[j] = rows[s*2+j][:] . wnT[:, col..col+3]
    float4 acc[2];
    acc[0] = make_float4(0.f, 0.f, 0.f, 0.f);
    acc[1] = make_float4(0.f, 0.f, 0.f, 0.f);
    {
        const float* wt = wnT + col;
        #pragma unroll 4
        for (int k4 = 0; k4 < DD / 4; ++k4) {
            const float4 w0 = *(const float4*)(wt + (size_t)(k4 * 4 + 0) * DD);
            const float4 w1 = *(const float4*)(wt + (size_t)(k4 * 4 + 1) * DD);
            const float4 w2 = *(const float4*)(wt + (size_t)(k4 * 4 + 2) * DD);
            const float4 w3 = *(const float4*)(wt + (size_t)(k4 * 4 + 3) * DD);
            #pragma unroll
            for (int j = 0; j < 2; ++j) {
                const float4 x = *(const float4*)&rows[s * 2 + j][k4 * 4];
                acc[j].x = fmaf(x.x, w0.x, fmaf(x.y, w1.x,
                           fmaf(x.z, w2.x, fmaf(x.w, w3.x, acc[j].x))));
                acc[j].y = fmaf(x.x, w0.y, fmaf(x.y, w1.y,
                           fmaf(x.z, w2.y, fmaf(x.w, w3.y, acc[j].y))));
                acc[j].z = fmaf(x.x, w0.z, fmaf(x.y, w1.z,
                           fmaf(x.z, w2.z, fmaf(x.w, w3.z, acc[j].z))));
                acc[j].w = fmaf(x.x, w0.w, fmaf(x.y, w1.w,
                           fmaf(x.z, w2.w, fmaf(x.w, w3.w, acc[j].w))));
            }
        }
    }

    // phase C: combined = nwn + pref * v_pref + daWd
    #pragma unroll
    for (int mm = 0; mm < MM; ++mm) {
        #pragma unroll
        for (int j = 0; j < 2; ++j) {
            const int node = n0 + s * 2 + j;
            if (node >= NNODES) continue;
            const float pr = pref_s[mm][s * 2 + j];
            float4 o;
            o.x = fmaf(pr, vp.x, acc[j].x + dawd[mm].x);
            o.y = fmaf(pr, vp.y, acc[j].y + dawd[mm].y);
            o.z = fmaf(pr, vp.z, acc[j].z + dawd[mm].z);
            o.w = fmaf(pr, vp.w, acc[j].w + dawd[mm].w);
            *(float4*)(out_comb +
                ((size_t)(b * MM + mm) * NNODES + node) * DD + col) = o;
        }
    }
}

extern "C" void kernel_launch(void* const* d_in, const int* in_sizes, int n_in,
                              void* d_out, int out_size, void* d_ws, size_t ws_size,
                              hipStream_t stream) {
    const float* locs        = (const float*)d_in[0];
    const float* capacity    = (const float*)d_in[1];
    const float* speed       = (const float*)d_in[2];
    const float* demand      = (const float*)d_in[3];
    const float* agents_pref = (const float*)d_in[4];
    // d_in[5] action_mask: only its shape is used by the reference
    const float* W_depot     = (const float*)d_in[6];
    const float* W_posproj   = (const float*)d_in[7];
    const float* alpha       = (const float*)d_in[8];
    const float* W_agents    = (const float*)d_in[9];
    const float* W_da        = (const float*)d_in[10];
    const float* W_clients   = (const float*)d_in[11];
    const float* W_pref      = (const float*)d_in[12];
    const float* W_final     = (const float*)d_in[13];

    float* out_nodes = (float*)d_out;                         // 32*1010*128
    float* out_comb  = out_nodes + (size_t)BB * NNODES * DD;  // 32*10*1010*128

    float* ws_daWd  = (float*)d_ws;                     // 40960 floats
    float* ws_vpref = ws_daWd + BB * MM * DD;           // 128
    float* ws_wnT   = ws_vpref + DD;                    // 16384

    k_front<<<dim3(49), 512, 0, stream>>>(
        locs, capacity, speed, W_depot, W_posproj, alpha, W_agents,
        W_da, W_pref, W_final, out_nodes, ws_daWd, ws_wnT, ws_vpref);

    k_back<<<dim3(NG, BB), 256, 0, stream>>>(
        locs, demand, agents_pref, W_clients, ws_wnT,
        ws_daWd, ws_vpref, out_nodes, out_comb);
}